// Round 1
// baseline (96.989 us; speedup 1.0000x reference)
//
#include <hip/hip_runtime.h>

// 2-qubit gate on qubits (5,12) of a 24-qubit f32 state with batch=4.
// Flat element index: 26 bits. Qubit-5 bit at position 20, qubit-12 bit at 13.
// In float4 units: bits 18 and 11.
__global__ __launch_bounds__(256) void gate_q5_q12_kernel(
    const float* __restrict__ state,
    const float* __restrict__ mat,   // [4][4][1] row-major, 16 floats
    float* __restrict__ out) {

    // Broadcast 4x4 gate matrix (uniform -> scalar loads, L2-resident)
    float m[4][4];
#pragma unroll
    for (int i = 0; i < 4; ++i)
#pragma unroll
        for (int j = 0; j < 4; ++j)
            m[i][j] = mat[i * 4 + j];

    const unsigned t = blockIdx.x * blockDim.x + threadIdx.x;  // [0, 2^22)

    // Insert zero bits at float4-positions 11 (qubit 12) and 18 (qubit 5).
    const unsigned low  = t & 0x7FFu;          // bits 0-10
    const unsigned mid  = (t >> 11) & 0x3Fu;   // -> bits 12-17
    const unsigned high = t >> 17;             // -> bits 19-23
    const unsigned base4 = low | (mid << 12) | (high << 19);

    const unsigned S12 = 1u << 11;  // 2^13 elements / 4
    const unsigned S5  = 1u << 18;  // 2^20 elements / 4

    const float4* __restrict__ s4 = (const float4*)state;
    float4* __restrict__ o4 = (float4*)out;

    // j = 2*b5 + b12
    float4 v0 = s4[base4];             // b5=0 b12=0 -> j=0
    float4 v1 = s4[base4 + S12];       // b5=0 b12=1 -> j=1
    float4 v2 = s4[base4 + S5];        // b5=1 b12=0 -> j=2
    float4 v3 = s4[base4 + S5 + S12];  // b5=1 b12=1 -> j=3

    float4 r0, r1, r2, r3;
    r0.x = m[0][0]*v0.x + m[0][1]*v1.x + m[0][2]*v2.x + m[0][3]*v3.x;
    r0.y = m[0][0]*v0.y + m[0][1]*v1.y + m[0][2]*v2.y + m[0][3]*v3.y;
    r0.z = m[0][0]*v0.z + m[0][1]*v1.z + m[0][2]*v2.z + m[0][3]*v3.z;
    r0.w = m[0][0]*v0.w + m[0][1]*v1.w + m[0][2]*v2.w + m[0][3]*v3.w;

    r1.x = m[1][0]*v0.x + m[1][1]*v1.x + m[1][2]*v2.x + m[1][3]*v3.x;
    r1.y = m[1][0]*v0.y + m[1][1]*v1.y + m[1][2]*v2.y + m[1][3]*v3.y;
    r1.z = m[1][0]*v0.z + m[1][1]*v1.z + m[1][2]*v2.z + m[1][3]*v3.z;
    r1.w = m[1][0]*v0.w + m[1][1]*v1.w + m[1][2]*v2.w + m[1][3]*v3.w;

    r2.x = m[2][0]*v0.x + m[2][1]*v1.x + m[2][2]*v2.x + m[2][3]*v3.x;
    r2.y = m[2][0]*v0.y + m[2][1]*v1.y + m[2][2]*v2.y + m[2][3]*v3.y;
    r2.z = m[2][0]*v0.z + m[2][1]*v1.z + m[2][2]*v2.z + m[2][3]*v3.z;
    r2.w = m[2][0]*v0.w + m[2][1]*v1.w + m[2][2]*v2.w + m[2][3]*v3.w;

    r3.x = m[3][0]*v0.x + m[3][1]*v1.x + m[3][2]*v2.x + m[3][3]*v3.x;
    r3.y = m[3][0]*v0.y + m[3][1]*v1.y + m[3][2]*v2.y + m[3][3]*v3.y;
    r3.z = m[3][0]*v0.z + m[3][1]*v1.z + m[3][2]*v2.z + m[3][3]*v3.z;
    r3.w = m[3][0]*v0.w + m[3][1]*v1.w + m[3][2]*v2.w + m[3][3]*v3.w;

    o4[base4]             = r0;  // i = 2*b5 + b12 = 0
    o4[base4 + S12]       = r1;  // i = 1
    o4[base4 + S5]        = r2;  // i = 2
    o4[base4 + S5 + S12]  = r3;  // i = 3
}

extern "C" void kernel_launch(void* const* d_in, const int* in_sizes, int n_in,
                              void* d_out, int out_size, void* d_ws, size_t ws_size,
                              hipStream_t stream) {
    const float* state = (const float*)d_in[0];  // 2^26 floats
    const float* mat   = (const float*)d_in[1];  // 16 floats
    float* out = (float*)d_out;

    const int nthreads = 1 << 22;   // one float4-group of 4 gathered float4s each
    const int block = 256;
    gate_q5_q12_kernel<<<nthreads / block, block, 0, stream>>>(state, mat, out);
}